// Round 8
// baseline (636.699 us; speedup 1.0000x reference)
//
#include <hip/hip_runtime.h>

#define HH 512
#define WW 512
#define SS (HH * WW)          // elements per plane (2^18)
#define P16N (16 * SS)        // 16 planes (2^22)

constexpr float FINF = 3.402823466e38f;

__device__ __forceinline__ int lswz(int j) { return j + (j >> 3); }

__device__ __forceinline__ float gray1(float r, float g, float b) {
    return 0.299f * r + 0.587f * g + 0.114f * b;
}

// ---------------- grad (gray fused, both dirs, 4 px/thread) ----------------
__global__ __launch_bounds__(256) void grad_both(const float* __restrict__ rgb,
                                                 float* __restrict__ dst,
                                                 int gxp0, int gyp0, int dirsel) {
    int sp = blockIdx.x * 256 + threadIdx.x;
    int idx = sp << 2;                             // [0, P16N)
    int img = idx >> 18;
    int pix = idx & (SS - 1);
    int i = pix >> 9, j0 = pix & (WW - 1);
    const float* p0 = rgb + (size_t)img * 3 * SS + pix;

    float4 r = *(const float4*)p0;
    float4 g = *(const float4*)(p0 + SS);
    float4 b = *(const float4*)(p0 + 2 * SS);
    float4 gy4 = make_float4(gray1(r.x, g.x, b.x), gray1(r.y, g.y, b.y),
                             gray1(r.z, g.z, b.z), gray1(r.w, g.w, b.w));
    if (dirsel != 1) {
        float grs = 0.f;
        if (j0 + 4 < WW) grs = gray1(p0[4], p0[SS + 4], p0[2 * SS + 4]);
        float4 gx = make_float4(gy4.x - gy4.y, gy4.y - gy4.z, gy4.z - gy4.w, gy4.w - grs);
        *(float4*)(dst + (size_t)(gxp0 + img) * SS + pix) = gx;
    }
    if (dirsel != 0) {
        float4 gd = make_float4(0.f, 0.f, 0.f, 0.f);
        if (i < HH - 1) {
            float4 r2 = *(const float4*)(p0 + WW);
            float4 g2 = *(const float4*)(p0 + SS + WW);
            float4 b2 = *(const float4*)(p0 + 2 * SS + WW);
            gd = make_float4(gray1(r2.x, g2.x, b2.x), gray1(r2.y, g2.y, b2.y),
                             gray1(r2.z, g2.z, b2.z), gray1(r2.w, g2.w, b2.w));
        }
        float4 gy = make_float4(gy4.x - gd.x, gy4.y - gd.y, gy4.z - gd.z, gy4.w - gd.w);
        *(float4*)(dst + (size_t)(gyp0 + img) * SS + pix) = gy;
    }
}

// ---------------- single avg pool, abs output (round-7 proven, TW=256) ----------------
template <int R>
__global__ __launch_bounds__(256) void avg_abs_pool(const float* __restrict__ src,
                                                    float* __restrict__ dst) {
    constexpr int ATH = 16, ATW = 256;
    constexpr int TILESH = WW / ATW;
    constexpr int LW = ATW + 2 * R;
    constexpr int PADL = LW + LW / 8 + 2;
    constexpr int NL2 = LW / 2;
    __shared__ float ls[ATH * PADL];

    const int plane = blockIdx.x / ((HH / ATH) * TILESH);
    const int rem   = blockIdx.x % ((HH / ATH) * TILESH);
    const int i0    = (rem / TILESH) * ATH;
    const int gj0   = (rem % TILESH) * ATW;
    const size_t pbase = (size_t)plane * SS;
    const float* sp = src + pbase;
    const int t = threadIdx.x;

    if (t < NL2) {
        const int lj = 2 * t;
        const int gj = gj0 - R + lj;
        const bool cin = (unsigned)gj < (unsigned)WW;
        auto ld = [&](int gi) -> float2 {
            if (cin && (unsigned)gi < (unsigned)HH)
                return *(const float2*)(sp + (size_t)gi * WW + gj);
            return make_float2(0.f, 0.f);
        };
        float2 acc = make_float2(0.f, 0.f);
        #pragma unroll
        for (int k = -R; k <= R; ++k) { float2 v = ld(i0 + k); acc.x += v.x; acc.y += v.y; }
        const int ca = lswz(lj);
        ls[ca] = acc.x; ls[ca + 1] = acc.y;
        #pragma unroll
        for (int oi = 1; oi < ATH; ++oi) {
            float2 a = ld(i0 + oi + R), s = ld(i0 + oi - R - 1);
            acc.x += a.x - s.x; acc.y += a.y - s.y;
            ls[oi * PADL + ca] = acc.x; ls[oi * PADL + ca + 1] = acc.y;
        }
    }
    __syncthreads();

    for (int s = t; s < ATH * (ATW / 8); s += 256) {
        int rr = s >> 5, j0l = (s & 31) << 3;
        int i = i0 + rr;
        int ch = min(i + R, HH - 1) - max(i - R, 0) + 1;
        const float* row = &ls[rr * PADL];
        float racc = 0.f;
        #pragma unroll
        for (int k = 0; k <= 2 * R; ++k) racc += row[lswz(j0l + k)];
        float ov[8];
        #pragma unroll
        for (int d = 0; d < 8; ++d) {
            if (d > 0) {
                racc += row[lswz(j0l + d + 2 * R)];
                racc -= row[lswz(j0l + d - 1)];
            }
            int gj = gj0 + j0l + d;
            int cw = min(gj + R, WW - 1) - max(gj - R, 0) + 1;
            ov[d] = fabsf(racc / (float)(ch * cw));
        }
        float4* d4 = (float4*)&dst[pbase + (size_t)i * WW + gj0 + j0l];
        d4[0] = make_float4(ov[0], ov[1], ov[2], ov[3]);
        d4[1] = make_float4(ov[4], ov[5], ov[6], ov[7]);
    }
}

// ---------------- fused dual(max/min,R1) -> avg(R2) chain + epilogue ----------------
// EPI 1 (gn1): out = (|e1| - avg(min))/(|avg(max) - avg(min)| + 1e-4)       [e1 = g]
// EPI 2 (map): out = ((e1 - avg(min))/(|avg(max)-avg(min)|+1e-4)+0.01)*e2  [e1=go, e2=gn1]
// Tile: 16 x 64 outputs. Valid-only window semantics throughout.
template <bool PREABS, int R1, int R2, int EPI>
__global__ __launch_bounds__(256) void fused_dual_avg(const float* __restrict__ src,
                                                      const float* __restrict__ e1,
                                                      const float* __restrict__ e2,
                                                      float* __restrict__ dst) {
    constexpr int FTH = 16, FTW = 64;
    constexpr int SR   = FTH + 2 * R2;             // strip rows
    constexpr int VCx  = FTW + 2 * (R1 + R2);      // exact v-pool cols
    constexpr int VC   = (VCx + 7) & ~7;           // padded to x8
    constexpr int PC   = FTW + 2 * R2;             // pmax cols
    constexpr int PADV = VC + VC / 8 + 2;
    constexpr int PADP = PC + PC / 8 + 2;
    constexpr int NSA  = VC / 8;                   // stage-A spans per row
    constexpr int NSB  = (PC + 7) / 8;             // stage-B spans per row

    __shared__ float VX[SR * PADV], VN[SR * PADV];
    __shared__ float PX[SR * PADP], PN[SR * PADP];
    float* SX = VX;                                // overlay: VX/VN dead after stage B
    float* SN = VN;                                // (16*PADP <= SR*PADV always here)

    const int plane = blockIdx.x / ((HH / FTH) * (WW / FTW));
    const int rem   = blockIdx.x % ((HH / FTH) * (WW / FTW));
    const int i0    = (rem / (WW / FTW)) * FTH;
    const int gj0   = (rem % (WW / FTW)) * FTW;
    const size_t pbase = (size_t)plane * SS;
    const float* sp = src + pbase;
    const int t = threadIdx.x;

    // ---- Stage A: vertical max+min over R1 from global (brute; L1 reuse) ----
    for (int s = t; s < SR * NSA; s += 256) {
        int rr = s / NSA, sp8 = s % NSA;
        int gi = i0 - R2 + rr;
        int gjb = gj0 - (R1 + R2) + 8 * sp8;       // even
        float mx[8], mn[8];
        #pragma unroll
        for (int d = 0; d < 8; ++d) { mx[d] = -FINF; mn[d] = FINF; }
        #pragma unroll
        for (int k = 0; k < 2 * R1 + 1; ++k) {
            int gr = gi - R1 + k;
            if ((unsigned)gr < (unsigned)HH) {
                const float* rowp = sp + (size_t)gr * WW;
                #pragma unroll
                for (int m = 0; m < 4; ++m) {
                    int gc = gjb + 2 * m * 1;      // float2 granularity
                    gc = gjb + 2 * m;
                    if ((unsigned)gc < (unsigned)WW) {
                        float2 v = *(const float2*)(rowp + gc);
                        if (PREABS) { v.x = fabsf(v.x); v.y = fabsf(v.y); }
                        mx[2*m]   = fmaxf(mx[2*m],   v.x);
                        mx[2*m+1] = fmaxf(mx[2*m+1], v.y);
                        mn[2*m]   = fminf(mn[2*m],   v.x);
                        mn[2*m+1] = fminf(mn[2*m+1], v.y);
                    }
                }
            }
        }
        float* vxr = &VX[rr * PADV];
        float* vnr = &VN[rr * PADV];
        #pragma unroll
        for (int d = 0; d < 8; ++d) {
            int lc = lswz(8 * sp8 + d);
            vxr[lc] = mx[d]; vnr[lc] = mn[d];
        }
    }
    __syncthreads();

    // ---- Stage B: horizontal max+min over R1; 0 at invalid positions ----
    for (int s = t; s < SR * NSB; s += 256) {
        int rr = s / NSB, sp8 = s % NSB;
        int p0 = 8 * sp8;
        int gi = i0 - R2 + rr;
        const float* vxr = &VX[rr * PADV];
        const float* vnr = &VN[rr * PADV];
        float wx[2 * R1 + 8], wn[2 * R1 + 8];
        #pragma unroll
        for (int k = 0; k < 2 * R1 + 8; ++k) {
            int lc = lswz(p0 + k);
            wx[k] = vxr[lc]; wn[k] = vnr[lc];
        }
        float* pxr = &PX[rr * PADP];
        float* pnr = &PN[rr * PADP];
        bool rok = (unsigned)gi < (unsigned)HH;
        #pragma unroll
        for (int d = 0; d < 8; ++d) {
            int p = p0 + d;
            if (p >= PC) break;
            float mx = wx[d], mn = wn[d];
            #pragma unroll
            for (int k = 1; k <= 2 * R1; ++k) { mx = fmaxf(mx, wx[d + k]); mn = fminf(mn, wn[d + k]); }
            int gj = gj0 - R2 + p;
            bool ok = rok && ((unsigned)gj < (unsigned)WW);
            pxr[lswz(p)] = ok ? mx : 0.f;
            pnr[lswz(p)] = ok ? mn : 0.f;
        }
    }
    __syncthreads();

    // ---- Stage C: vertical sliding sums over R2 (col-walk, two halves) ----
    if (t < 2 * PC) {
        int p = t % PC, h = t / PC;                // h in {0,1}
        int lc = lswz(p);
        float ax = 0.f, an = 0.f;
        #pragma unroll
        for (int k = 0; k < 2 * R2 + 1; ++k) {
            ax += PX[(8 * h + k) * PADP + lc];
            an += PN[(8 * h + k) * PADP + lc];
        }
        SX[(8 * h) * PADP + lc] = ax;
        SN[(8 * h) * PADP + lc] = an;
        #pragma unroll
        for (int o2 = 1; o2 < 8; ++o2) {
            int oi = 8 * h + o2;
            ax += PX[(oi + 2 * R2) * PADP + lc] - PX[(oi - 1) * PADP + lc];
            an += PN[(oi + 2 * R2) * PADP + lc] - PN[(oi - 1) * PADP + lc];
            SX[oi * PADP + lc] = ax;
            SN[oi * PADP + lc] = an;
        }
    }
    __syncthreads();

    // ---- Stage D: horizontal sliding sums + valid-count divide + epilogue ----
    {
        int oi  = t >> 4;                          // 16 rows
        int q   = t & 15;                          // 16 groups of 4 cols
        int j0l = 4 * q;
        int gi  = i0 + oi;
        int ch  = min(gi + R2, HH - 1) - max(gi - R2, 0) + 1;
        const float* sxr = &SX[oi * PADP];
        const float* snr = &SN[oi * PADP];
        float wxs = 0.f, wns = 0.f;
        #pragma unroll
        for (int k = 0; k < 2 * R2 + 1; ++k) {
            int lc = lswz(j0l + k);
            wxs += sxr[lc]; wns += snr[lc];
        }
        size_t obase = pbase + (size_t)gi * WW + gj0 + j0l;
        float4 ev1 = *(const float4*)(e1 + obase);
        float4 ev2 = make_float4(0.f, 0.f, 0.f, 0.f);
        if (EPI == 2) ev2 = *(const float4*)(e2 + obase);
        const float* e1p = (const float*)&ev1;
        const float* e2p = (const float*)&ev2;
        float o[4];
        #pragma unroll
        for (int d = 0; d < 4; ++d) {
            if (d > 0) {
                int la = lswz(j0l + d + 2 * R2), lb = lswz(j0l + d - 1);
                wxs += sxr[la] - sxr[lb];
                wns += snr[la] - snr[lb];
            }
            int gj = gj0 + j0l + d;
            int cw = min(gj + R2, WW - 1) - max(gj - R2, 0) + 1;
            float inv = 1.f / (float)(ch * cw);
            float mx = wxs * inv, mn = wns * inv;
            float den = fabsf(mx - mn) + 1e-4f;
            if (EPI == 1) o[d] = (fabsf(e1p[d]) - mn) / den;
            else          o[d] = ((e1p[d] - mn) / den + 0.01f) * e2p[d];
        }
        *(float4*)(dst + obase) = make_float4(o[0], o[1], o[2], o[3]);
    }
}

// ---------------- reduction ----------------
// Layout: [seg0_a(16 planes)|seg0_b|seg1_a|seg1_b]; pairs a=M[seg*2^23+off],
// b = a + 2^22. Works for n=2^22 (seg 0 only) and 2^23.
__global__ __launch_bounds__(256) void reduce1(const float* __restrict__ M,
                                               float* __restrict__ partials, int n4) {
    int tid = blockIdx.x * 256 + threadIdx.x;
    float v = 0.f;
    for (int q = tid; q < n4; q += 256 * 1024) {
        int i = q << 2;
        int seg = i >> 22;
        int off = i & ((1 << 22) - 1);
        size_t aidx = ((size_t)seg << 23) + (size_t)off;
        float4 a = *(const float4*)(M + aidx);
        float4 b = *(const float4*)(M + aidx + (1u << 22));
        v += a.x * expf(-10.f * (a.x + b.x));
        v += a.y * expf(-10.f * (a.y + b.y));
        v += a.z * expf(-10.f * (a.z + b.z));
        v += a.w * expf(-10.f * (a.w + b.w));
    }
    for (int off = 32; off; off >>= 1) v += __shfl_down(v, off);
    __shared__ float lds[4];
    int lane = threadIdx.x & 63, wv = threadIdx.x >> 6;
    if (lane == 0) lds[wv] = v;
    __syncthreads();
    if (threadIdx.x == 0) partials[blockIdx.x] = lds[0] + lds[1] + lds[2] + lds[3];
}

__global__ __launch_bounds__(256) void reduce2(const float* __restrict__ partials,
                                               float* __restrict__ out, float scale, int n) {
    float v = 0.f;
    for (int i = threadIdx.x; i < n; i += 256) v += partials[i];
    for (int off = 32; off; off >>= 1) v += __shfl_down(v, off);
    __shared__ float lds[4];
    int lane = threadIdx.x & 63, wv = threadIdx.x >> 6;
    if (lane == 0) lds[wv] = v;
    __syncthreads();
    if (threadIdx.x == 0) atomicAdd(out, (lds[0] + lds[1] + lds[2] + lds[3]) * scale);
}

// ---------------- host orchestration ----------------

// G holds g on entry; gn1 -> C; go -> A; final map -> G (g dead by then).
static void pool_pipeline(float* G, float* A, float* C, int planes, hipStream_t s) {
    int gf = planes * (HH / 16) * (WW / 64);       // fused tiles
    int ga = planes * (HH / 16) * (WW / 256);      // avg_abs tiles
    fused_dual_avg<true , 4, 8, 1><<<gf, 256, 0, s>>>(G, G, nullptr, C);  // C = gn1
    avg_abs_pool<2><<<ga, 256, 0, s>>>(G, A);                             // A = go
    fused_dual_avg<false, 3, 3, 2><<<gf, 256, 0, s>>>(A, A, C, G);        // G = map
}

extern "C" void kernel_launch(void* const* d_in, const int* in_sizes, int n_in,
                              void* d_out, int out_size, void* d_ws, size_t ws_size,
                              hipStream_t stream) {
    const float* Rrgb = (const float*)d_in[0];
    const float* Lrgb = (const float*)d_in[1];
    float* out = (float*)d_out;
    float* w = (float*)d_ws;
    const float scale = 1.f / (float)P16N;
    const int gradblk = (P16N / 4 + 255) / 256;

    hipMemsetAsync(out, 0, sizeof(float) * (size_t)out_size, stream);

    const size_t stack64 = (size_t)64 * SS;
    if (ws_size >= 3 * stack64 * sizeof(float) + 1024 * sizeof(float)) {
        // 3 buffers of 64 planes: [0..16)=Rgx [16..32)=Lgx [32..48)=Rgy [48..64)=Lgy
        float* G = w;
        float* A = G + stack64;
        float* C = A + stack64;
        float* partials = C + stack64;
        grad_both<<<gradblk, 256, 0, stream>>>(Rrgb, G, 0, 32, 2);
        grad_both<<<gradblk, 256, 0, stream>>>(Lrgb, G, 16, 48, 2);
        pool_pipeline(G, A, C, 64, stream);
        reduce1<<<1024, 256, 0, stream>>>(G, partials, (2 * P16N) / 4);
        reduce2<<<1, 256, 0, stream>>>(partials, out, scale, 1024);
    } else {
        // fallback: 3 buffers of 32 planes (~100 MB), one direction at a time
        const size_t stack32 = (size_t)32 * SS;
        float* G = w;
        float* A = G + stack32;
        float* C = A + stack32;
        float* partials = C + stack32;
        for (int dir = 0; dir < 2; ++dir) {
            grad_both<<<gradblk, 256, 0, stream>>>(Rrgb, G, 0, 0, dir);
            grad_both<<<gradblk, 256, 0, stream>>>(Lrgb, G, 16, 16, dir);
            pool_pipeline(G, A, C, 32, stream);
            reduce1<<<1024, 256, 0, stream>>>(G, partials, P16N / 4);
            reduce2<<<1, 256, 0, stream>>>(partials, out, scale, 1024);
        }
    }
}